// Round 9
// baseline (32.477 us; speedup 1.0000x reference)
//
#include <hip/hip_runtime.h>
#include <math.h>

// Ordinal regression loss: mean over (B, K=4) of
//   max(x,0) - x*[k < label] + log1p(exp(-|x|))  ==  softplus(s*x), s=+-1
// Two-kernel streaming reduction (all fusion variants regressed:
// r2 fences 100us, r4 memset-node 52us, r5 atomic-ticket 37.5us).
// Round 9: block-local 8-row unroll (TILE=2048, 160B/lane in flight),
// single-wave final kernel (no barrier, pure shuffle tree).

#define KDIM 4
#define BLOCK 256
#define GRID 2048
#define ROWS 8                      // rows per thread per outer iter
#define TILE (ROWS * BLOCK)         // 2048 rows per block per outer iter

typedef float f32x4 __attribute__((ext_vector_type(4)));

__device__ __forceinline__ float row_loss(f32x4 x, int lab) {
    float acc = 0.0f;
#pragma unroll
    for (int k = 0; k < KDIM; ++k) {
        float v = x[k];
        // BCE-with-logits == softplus(z), z = (target ? -v : v)
        float z = (k < lab) ? -v : v;
        float a = fabsf(v);
        // softplus(z) = max(z,0) + log1p(exp(-|z|)), |z| == |v|
        acc += fmaxf(z, 0.0f) + __logf(1.0f + __expf(-a));
    }
    return acc;
}

__global__ __launch_bounds__(BLOCK) void ordloss_partial(
    const f32x4* __restrict__ logits,    // B rows, one float4 per row (K=4)
    const int* __restrict__ labels,      // B int32
    float* __restrict__ partial,         // GRID floats
    int B)
{
    const int t = threadIdx.x;
    const long ostride = (long)GRID * TILE;

    float acc = 0.0f;
    for (long base = (long)blockIdx.x * TILE; base < B; base += ostride) {
        if (base + TILE <= B) {
            // fast path: 8 coalesced f32x4 + 8 coalesced int, branch-free
            f32x4 x[ROWS];
            int   l[ROWS];
#pragma unroll
            for (int r = 0; r < ROWS; ++r)
                x[r] = __builtin_nontemporal_load(logits + base + r * BLOCK + t);
#pragma unroll
            for (int r = 0; r < ROWS; ++r)
                l[r] = __builtin_nontemporal_load(labels + base + r * BLOCK + t);
#pragma unroll
            for (int r = 0; r < ROWS; ++r)
                acc += row_loss(x[r], l[r]);
        } else {
#pragma unroll
            for (int r = 0; r < ROWS; ++r) {
                long i = base + r * BLOCK + t;
                if (i < B) {
                    f32x4 xx = __builtin_nontemporal_load(logits + i);
                    int ll = __builtin_nontemporal_load(labels + i);
                    acc += row_loss(xx, ll);
                }
            }
        }
    }

    // wave64 shuffle reduction
#pragma unroll
    for (int off = 32; off > 0; off >>= 1)
        acc += __shfl_down(acc, off, 64);

    __shared__ float wsum[BLOCK / 64];
    int lane = threadIdx.x & 63;
    int wid  = threadIdx.x >> 6;
    if (lane == 0) wsum[wid] = acc;
    __syncthreads();
    if (threadIdx.x == 0) {
        float s = wsum[0] + wsum[1] + wsum[2] + wsum[3];
        partial[blockIdx.x] = s;
    }
}

__global__ __launch_bounds__(64) void ordloss_final(
    const f32x4* __restrict__ partial4,  // GRID/4 = 512 float4s
    float* __restrict__ out, float inv_count)
{
    // one wave: 64 threads x 8 float4 = 2048 floats, no barrier needed
    const int t = threadIdx.x;
    f32x4 v[8];
#pragma unroll
    for (int j = 0; j < 8; ++j)
        v[j] = partial4[t + j * 64];
    float acc = 0.0f;
#pragma unroll
    for (int j = 0; j < 8; ++j)
        acc += (v[j][0] + v[j][1]) + (v[j][2] + v[j][3]);

#pragma unroll
    for (int off = 32; off > 0; off >>= 1)
        acc += __shfl_down(acc, off, 64);

    if (t == 0)
        out[0] = acc * inv_count;
}

extern "C" void kernel_launch(void* const* d_in, const int* in_sizes, int n_in,
                              void* d_out, int out_size, void* d_ws, size_t ws_size,
                              hipStream_t stream) {
    const f32x4* logits = (const f32x4*)d_in[0];
    const int*   labels = (const int*)d_in[1];
    float*       out    = (float*)d_out;
    float*       partial = (float*)d_ws;   // GRID floats = 8 KiB

    int B = in_sizes[1];  // labels count = rows
    float inv_count = 1.0f / ((float)B * (float)KDIM);

    ordloss_partial<<<GRID, BLOCK, 0, stream>>>(logits, labels, partial, B);
    ordloss_final<<<1, 64, 0, stream>>>((const f32x4*)partial, out, inv_count);
}

// Round 10
// 31.467 us; speedup vs baseline: 1.0321x; 1.0321x over previous
//
#include <hip/hip_runtime.h>
#include <math.h>

// Ordinal regression loss: mean over (B, K=4) of
//   max(x,0) - x*[k < label] + log1p(exp(-|x|))  ==  softplus(s*x), s=+-1
// Two-kernel streaming reduction (all fusion variants regressed:
// r2 fences 100us, r4 memset-node 52us, r5 atomic-ticket 37.5us).
// Round 10 (final): ROWS=4 block-local unroll (round-8 champion; ROWS=8
// regressed) + single-wave barrier-free final kernel.

#define KDIM 4
#define BLOCK 256
#define GRID 2048
#define ROWS 4                      // rows per thread per outer iter (sweet spot)
#define TILE (ROWS * BLOCK)         // 1024 rows per block per outer iter

typedef float f32x4 __attribute__((ext_vector_type(4)));

__device__ __forceinline__ float row_loss(f32x4 x, int lab) {
    float acc = 0.0f;
#pragma unroll
    for (int k = 0; k < KDIM; ++k) {
        float v = x[k];
        // BCE-with-logits == softplus(z), z = (target ? -v : v)
        float z = (k < lab) ? -v : v;
        float a = fabsf(v);
        // softplus(z) = max(z,0) + log1p(exp(-|z|)), |z| == |v|
        acc += fmaxf(z, 0.0f) + __logf(1.0f + __expf(-a));
    }
    return acc;
}

__global__ __launch_bounds__(BLOCK) void ordloss_partial(
    const f32x4* __restrict__ logits,    // B rows, one float4 per row (K=4)
    const int* __restrict__ labels,      // B int32
    float* __restrict__ partial,         // GRID floats
    int B)
{
    const int t = threadIdx.x;
    const long ostride = (long)GRID * TILE;

    float acc = 0.0f;
    for (long base = (long)blockIdx.x * TILE; base < B; base += ostride) {
        if (base + TILE <= B) {
            // fast path: branch-free, 4 coalesced f32x4 + 4 coalesced int
            f32x4 x0 = __builtin_nontemporal_load(logits + base + 0 * BLOCK + t);
            f32x4 x1 = __builtin_nontemporal_load(logits + base + 1 * BLOCK + t);
            f32x4 x2 = __builtin_nontemporal_load(logits + base + 2 * BLOCK + t);
            f32x4 x3 = __builtin_nontemporal_load(logits + base + 3 * BLOCK + t);
            int l0 = __builtin_nontemporal_load(labels + base + 0 * BLOCK + t);
            int l1 = __builtin_nontemporal_load(labels + base + 1 * BLOCK + t);
            int l2 = __builtin_nontemporal_load(labels + base + 2 * BLOCK + t);
            int l3 = __builtin_nontemporal_load(labels + base + 3 * BLOCK + t);
            acc += row_loss(x0, l0);
            acc += row_loss(x1, l1);
            acc += row_loss(x2, l2);
            acc += row_loss(x3, l3);
        } else {
#pragma unroll
            for (int r = 0; r < ROWS; ++r) {
                long i = base + r * BLOCK + t;
                if (i < B) {
                    f32x4 x = __builtin_nontemporal_load(logits + i);
                    int l = __builtin_nontemporal_load(labels + i);
                    acc += row_loss(x, l);
                }
            }
        }
    }

    // wave64 shuffle reduction
#pragma unroll
    for (int off = 32; off > 0; off >>= 1)
        acc += __shfl_down(acc, off, 64);

    __shared__ float wsum[BLOCK / 64];
    int lane = threadIdx.x & 63;
    int wid  = threadIdx.x >> 6;
    if (lane == 0) wsum[wid] = acc;
    __syncthreads();
    if (threadIdx.x == 0) {
        float s = wsum[0] + wsum[1] + wsum[2] + wsum[3];
        partial[blockIdx.x] = s;
    }
}

__global__ __launch_bounds__(64) void ordloss_final(
    const f32x4* __restrict__ partial4,  // GRID/4 = 512 float4s
    float* __restrict__ out, float inv_count)
{
    // one wave: 64 threads x 8 float4 = 2048 floats, no barrier needed
    const int t = threadIdx.x;
    f32x4 v[8];
#pragma unroll
    for (int j = 0; j < 8; ++j)
        v[j] = partial4[t + j * 64];
    float acc = 0.0f;
#pragma unroll
    for (int j = 0; j < 8; ++j)
        acc += (v[j][0] + v[j][1]) + (v[j][2] + v[j][3]);

#pragma unroll
    for (int off = 32; off > 0; off >>= 1)
        acc += __shfl_down(acc, off, 64);

    if (t == 0)
        out[0] = acc * inv_count;
}

extern "C" void kernel_launch(void* const* d_in, const int* in_sizes, int n_in,
                              void* d_out, int out_size, void* d_ws, size_t ws_size,
                              hipStream_t stream) {
    const f32x4* logits = (const f32x4*)d_in[0];
    const int*   labels = (const int*)d_in[1];
    float*       out    = (float*)d_out;
    float*       partial = (float*)d_ws;   // GRID floats = 8 KiB

    int B = in_sizes[1];  // labels count = rows
    float inv_count = 1.0f / ((float)B * (float)KDIM);

    ordloss_partial<<<GRID, BLOCK, 0, stream>>>(logits, labels, partial, B);
    ordloss_final<<<1, 64, 0, stream>>>((const f32x4*)partial, out, inv_count);
}